// Round 10
// baseline (497.376 us; speedup 1.0000x reference)
//
#include <hip/hip_runtime.h>
#include <stdint.h>

typedef int   i32x4 __attribute__((ext_vector_type(4)));
typedef float f32x4 __attribute__((ext_vector_type(4)));

#define AS1 __attribute__((address_space(1)))
#define AS3 __attribute__((address_space(3)))
#define G2L16(gp, lp) __builtin_amdgcn_global_load_lds((const AS1 void*)(gp), (AS3 void*)(lp), 16, 0, 0)

// ---------------- symmetric int8 row quantization (at BW floor) ----------------
template<int COLS>
__global__ __launch_bounds__(256)
void quant_rows_k(const float* __restrict__ src, int8_t* __restrict__ q,
                  float* __restrict__ scale)
{
    constexpr int PER = COLS / 256;   // 16
    static_assert(PER == 16, "pack assumes 16 elems/thread");
    const int row = blockIdx.x;
    const int t   = threadIdx.x;
    const float* s = src + (size_t)row * COLS + (size_t)t * PER;

    float v[PER];
    #pragma unroll
    for (int i = 0; i < PER; i += 4) {
        f32x4 x4 = *reinterpret_cast<const f32x4*>(s + i);
        v[i+0] = x4[0]; v[i+1] = x4[1]; v[i+2] = x4[2]; v[i+3] = x4[3];
    }
    float amax = 0.0f;
    #pragma unroll
    for (int i = 0; i < PER; ++i) amax = fmaxf(amax, fabsf(v[i]));

    #pragma unroll
    for (int off = 32; off > 0; off >>= 1)
        amax = fmaxf(amax, __shfl_xor(amax, off, 64));

    __shared__ float red[4];
    if ((t & 63) == 0) red[t >> 6] = amax;
    __syncthreads();
    amax = fmaxf(fmaxf(red[0], red[1]), fmaxf(red[2], red[3]));

    const float sc = fmaxf(amax, 1e-8f) / 127.0f;
    if (t == 0) scale[row] = sc;

    union { i32x4 v4; int8_t b[16]; } pk;
    #pragma unroll
    for (int i = 0; i < PER; ++i) {
        float r = rintf(v[i] / sc);
        r = fminf(127.0f, fmaxf(-127.0f, r));
        pk.b[i] = (int8_t)r;
    }
    *reinterpret_cast<i32x4*>(q + (size_t)row * COLS + (size_t)t * PER) = pk.v4;
}

// ---------------- int8 GEMM, 128x128 tile, 4 blocks/CU cross-block TLP ----------------
// 256 threads = 4 waves (2M x 2N), wave tile 64x64, BK = 64 B (one x64 k-slice).
// LDS 32 KiB (2 dbuf x (A 8K + B 8K)); __launch_bounds__(256,4) caps VGPR at 128
// -> 4 blocks/CU, 4 waves/SIMD, all from INDEPENDENT blocks: one block's
// vmcnt/barrier drain hides under the other blocks' MFMA+LDS work (m97/m114
// mechanism). Schedule per K-tile is deliberately simple (1 phase):
//   {stage 4 G2L (tile t+1, other buf); 8 ds_read; 16 MFMA; vmcnt(0); BAR}
// vmcnt(0) is issued a full tile after the G2Ls (long cover) and the stall is
// covered by the other resident blocks.
// LDS swizzle for 64B rows: chunk' = chunk ^ ((row>>1)&3) -> fragment reads are
// exactly 2-way bank-aliased (free, m136). G2L dest linear; SOURCE pre-swizzled.
#define BM 128
#define BN 128
#define BKB 64

__device__ __forceinline__ i32x4 mfma16(i32x4 a, i32x4 b, i32x4 c) {
    return __builtin_amdgcn_mfma_i32_16x16x64_i8(a, b, c, 0, 0, 0);
}
__device__ __forceinline__ i32x4 ldsld(const int8_t* p) {
    return *reinterpret_cast<const i32x4*>(p);
}
#define FENCE asm volatile("" ::: "memory")
#define BAR   do { FENCE; __builtin_amdgcn_s_barrier(); FENCE; } while (0)

template<bool ST>
__device__ __forceinline__ void tile_fn(
    const int8_t* __restrict__ aB, const int8_t* __restrict__ bB,  // per-thread frag bases (cur buf)
    i32x4 (&acc)[4][4],
    const int8_t* __restrict__ gA, const int8_t* __restrict__ gB,  // per-thread stage src (next tile)
    int8_t* lAn, int8_t* lBn,                                      // next-buf LDS bases
    size_t r64, int t16)
{
    if (ST) {   // stage tile t+1 into the other buffer (4 G2L, 16 KB total)
        G2L16(gA,       lAn + t16);
        G2L16(gA + r64, lAn + 4096 + t16);
        G2L16(gB,       lBn + t16);
        G2L16(gB + r64, lBn + 4096 + t16);
    }
    // fragment reads: A m=0..3 (rows m*16), B n=0..3 -- 8 x ds_read_b128, 2-way banks
    i32x4 a0 = ldsld(aB + 0*1024);
    i32x4 a1 = ldsld(aB + 1*1024);
    i32x4 a2 = ldsld(aB + 2*1024);
    i32x4 a3 = ldsld(aB + 3*1024);
    i32x4 b0 = ldsld(bB + 0*1024);
    i32x4 b1 = ldsld(bB + 1*1024);
    i32x4 b2 = ldsld(bB + 2*1024);
    i32x4 b3 = ldsld(bB + 3*1024);
    // 16 MFMA (compiler inserts counted lgkmcnt before first consumer)
    acc[0][0] = mfma16(a0, b0, acc[0][0]);
    acc[1][0] = mfma16(a1, b0, acc[1][0]);
    acc[2][0] = mfma16(a2, b0, acc[2][0]);
    acc[3][0] = mfma16(a3, b0, acc[3][0]);
    acc[0][1] = mfma16(a0, b1, acc[0][1]);
    acc[1][1] = mfma16(a1, b1, acc[1][1]);
    acc[2][1] = mfma16(a2, b1, acc[2][1]);
    acc[3][1] = mfma16(a3, b1, acc[3][1]);
    acc[0][2] = mfma16(a0, b2, acc[0][2]);
    acc[1][2] = mfma16(a1, b2, acc[1][2]);
    acc[2][2] = mfma16(a2, b2, acc[2][2]);
    acc[3][2] = mfma16(a3, b2, acc[3][2]);
    acc[0][3] = mfma16(a0, b3, acc[0][3]);
    acc[1][3] = mfma16(a1, b3, acc[1][3]);
    acc[2][3] = mfma16(a2, b3, acc[2][3]);
    acc[3][3] = mfma16(a3, b3, acc[3][3]);
    // next tile resident (RAW); reads above already in regs before re-stage (WAR)
    asm volatile("s_waitcnt vmcnt(0)" ::: "memory");
    BAR;
}

__global__ __launch_bounds__(256, 4)
void gemm_i8_k(const int8_t* __restrict__ A,    // [M][K]
               const int8_t* __restrict__ B,    // [N][K]
               const float*  __restrict__ sx,   // [M]
               const float*  __restrict__ sw,   // [N]
               const float*  __restrict__ bias, // [N]
               float* __restrict__ C,           // [M][N]
               int M, int N, int K)
{
    __shared__ int8_t lA[2][BM * BKB];   // 2 x 8 KiB
    __shared__ int8_t lB[2][BN * BKB];   // 2 x 8 KiB

    const int t    = threadIdx.x;
    const int lane = t & 63;
    const int wid  = t >> 6;
    const int wm   = wid >> 1;   // 0..1
    const int wn   = wid & 1;    // 0..1

    // bijective XCD swizzle (nwg = 4096, multiple of 8)
    const int nwg = (int)gridDim.x;
    const int bid = (int)blockIdx.x;
    const int swz = ((nwg & 7) == 0) ? ((bid & 7) * (nwg >> 3) + (bid >> 3)) : bid;
    const int nbn = N / BN;
    const int bm  = swz / nbn;
    const int bn  = swz % nbn;

    // fragment-read addressing: row = (wave 64-off) + m*16 + fr, 64B rows,
    // chunk kc = (c4 ^ ((fr>>1)&3))*16  (m*16 and wm*64 don't change (row>>1)&3)
    const int fr = lane & 15;
    const int c4 = lane >> 4;
    const int kc = ((c4 ^ ((fr >> 1) & 3)) << 4);
    const int aOff = (wm * 64 + fr) * BKB + kc;
    const int bOff = (wn * 64 + fr) * BKB + kc;
    const int8_t* aB0 = &lA[0][aOff];
    const int8_t* aB1 = &lA[1][aOff];
    const int8_t* bB0 = &lB[0][bOff];
    const int8_t* bB1 = &lB[1][bOff];

    // staging: slot s = i*256 + t (i=0,1) -> row = i*64 + (t>>2), chunk = t&3;
    // global source chunk pre-swizzled: cg = (t&3) ^ ((t>>3)&3)  ((row>>1)&3 == (t>>3)&3)
    const int srow = t >> 2;                               // 0..63
    const int scg  = (((t & 3) ^ ((t >> 3) & 3)) << 4);
    const int t16  = t * 16;
    const int8_t* pA = A + (size_t)(bm * BM + srow) * K + scg;
    const int8_t* pB = B + (size_t)(bn * BN + srow) * K + scg;
    const size_t r64 = (size_t)64 * K;

    // prologue: stage K-tile 0 into buffer 0
    G2L16(pA,       &lA[0][0]    + t16);
    G2L16(pA + r64, &lA[0][4096] + t16);
    G2L16(pB,       &lB[0][0]    + t16);
    G2L16(pB + r64, &lB[0][4096] + t16);
    asm volatile("s_waitcnt vmcnt(0)" ::: "memory");
    BAR;

    i32x4 acc[4][4] = {};

    const int NT = K / BKB;   // 64 (even)
    for (int tt = 0; tt + 2 < NT; tt += 2) {
        const size_t ko1 = (size_t)(tt + 1) * BKB;
        tile_fn<true>(aB0, bB0, acc, pA + ko1, pB + ko1, &lA[1][0], &lB[1][0], r64, t16);
        const size_t ko2 = (size_t)(tt + 2) * BKB;
        tile_fn<true>(aB1, bB1, acc, pA + ko2, pB + ko2, &lA[0][0], &lB[0][0], r64, t16);
    }
    {   // last two tiles: NT-2 (stages NT-1), then NT-1 (no stage)
        const size_t ko1 = (size_t)(NT - 1) * BKB;
        tile_fn<true >(aB0, bB0, acc, pA + ko1, pB + ko1, &lA[1][0], &lB[1][0], r64, t16);
        tile_fn<false>(aB1, bB1, acc, pA, pB, &lA[0][0], &lB[0][0], r64, t16);
    }

    // epilogue: dequant + bias
    const int r0 = bm * BM + wm * 64 + (c4 << 2);
    const int c0 = bn * BN + wn * 64 + fr;
    #pragma unroll
    for (int ni = 0; ni < 4; ++ni) {
        const int c = c0 + ni * 16;
        const float swc = sw[c];
        const float bc  = bias[c];
        #pragma unroll
        for (int mi = 0; mi < 4; ++mi) {
            const int rb = r0 + mi * 16;
            #pragma unroll
            for (int j = 0; j < 4; ++j) {
                const int r = rb + j;
                C[(size_t)r * N + c] = (float)acc[mi][ni][j] * sx[r] * swc + bc;
            }
        }
    }
}

extern "C" void kernel_launch(void* const* d_in, const int* in_sizes, int n_in,
                              void* d_out, int out_size, void* d_ws, size_t ws_size,
                              hipStream_t stream) {
    const float* x    = (const float*)d_in[0];
    const float* w    = (const float*)d_in[1];
    const float* bias = (const float*)d_in[2];
    float* out = (float*)d_out;

    const int dout   = in_sizes[2];          // 16384
    const int din    = in_sizes[1] / dout;   // 4096
    const int tokens = in_sizes[0] / din;    // 4096

    char* ws = (char*)d_ws;
    float*  sx = (float*)ws;
    float*  sw = (float*)(ws + 16384);
    int8_t* xq = (int8_t*)(ws + 16384 + 65536);
    int8_t* wq = xq + (size_t)tokens * din;

    quant_rows_k<4096><<<tokens, 256, 0, stream>>>(x, xq, sx);
    quant_rows_k<4096><<<dout,   256, 0, stream>>>(w, wq, sw);

    const int grid = (tokens / BM) * (dout / BN);   // 32 * 128 = 4096
    gemm_i8_k<<<grid, 256, 0, stream>>>(xq, wq, sx, sw, bias, out, tokens, dout, din);
}

// Round 11
// 441.082 us; speedup vs baseline: 1.1276x; 1.1276x over previous
//
#include <hip/hip_runtime.h>
#include <stdint.h>

typedef int   i32x4 __attribute__((ext_vector_type(4)));
typedef float f32x4 __attribute__((ext_vector_type(4)));

#define AS1 __attribute__((address_space(1)))
#define AS3 __attribute__((address_space(3)))
#define G2L16(gp, lp) __builtin_amdgcn_global_load_lds((const AS1 void*)(gp), (AS3 void*)(lp), 16, 0, 0)

// ---------------- symmetric int8 row quantization (at BW floor) ----------------
template<int COLS>
__global__ __launch_bounds__(256)
void quant_rows_k(const float* __restrict__ src, int8_t* __restrict__ q,
                  float* __restrict__ scale)
{
    constexpr int PER = COLS / 256;   // 16
    static_assert(PER == 16, "pack assumes 16 elems/thread");
    const int row = blockIdx.x;
    const int t   = threadIdx.x;
    const float* s = src + (size_t)row * COLS + (size_t)t * PER;

    float v[PER];
    #pragma unroll
    for (int i = 0; i < PER; i += 4) {
        f32x4 x4 = *reinterpret_cast<const f32x4*>(s + i);
        v[i+0] = x4[0]; v[i+1] = x4[1]; v[i+2] = x4[2]; v[i+3] = x4[3];
    }
    float amax = 0.0f;
    #pragma unroll
    for (int i = 0; i < PER; ++i) amax = fmaxf(amax, fabsf(v[i]));

    #pragma unroll
    for (int off = 32; off > 0; off >>= 1)
        amax = fmaxf(amax, __shfl_xor(amax, off, 64));

    __shared__ float red[4];
    if ((t & 63) == 0) red[t >> 6] = amax;
    __syncthreads();
    amax = fmaxf(fmaxf(red[0], red[1]), fmaxf(red[2], red[3]));

    const float sc = fmaxf(amax, 1e-8f) / 127.0f;
    if (t == 0) scale[row] = sc;

    union { i32x4 v4; int8_t b[16]; } pk;
    #pragma unroll
    for (int i = 0; i < PER; ++i) {
        float r = rintf(v[i] / sc);
        r = fminf(127.0f, fmaxf(-127.0f, r));
        pk.b[i] = (int8_t)r;
    }
    *reinterpret_cast<i32x4*>(q + (size_t)row * COLS + (size_t)t * PER) = pk.v4;
}

// ---------------- int8 GEMM, 256x256 tile, DEPTH-3 PIPELINE (4-deep LDS ring) ----------------
// 512 threads = 8 waves (2M x 4N), wave tile 128x64, BK = 64 B (one x64 k-slice).
// LDS ring: 4 bufs x (A 16K + B 16K) = 128 KiB. Per K-tile t:
//   {stage tile t+3 into buf[(t+3)&3] (4 G2L); 12 ds_read from buf[t&3];
//    32 MFMA; vmcnt(8); BAR}
// Steady-state vmcnt(8) drains ONLY tile t+1's 4 loads, which were issued TWO
// full tiles (~4000 cy) earlier -> HBM/L2 latency fully covered at every drain
// (m201's depth-3 property; my r2-r8 drains had only ~1-phase cover).
// Epilogue ramp: vmcnt 8 -> 4 -> 0 -> none. One barrier + one counted vmcnt
// per tile; no lgkmcnt(0)/sched_barrier (compiler emits counted lgkm).
// Ledger (per wave): RAW -- tile t's buf drained by end-of-(t-1) vmcnt(8)
// (12 outstanding -> 8 keeps t+2,t+3; drains t+1) + barrier. WAR -- buf[b]
// re-staged >= 1 barrier after its last read (reads complete pre-MFMA pre-BAR).
#define BM 256
#define BN 256
#define BKB 64

__device__ __forceinline__ i32x4 mfma16(i32x4 a, i32x4 b, i32x4 c) {
    return __builtin_amdgcn_mfma_i32_16x16x64_i8(a, b, c, 0, 0, 0);
}
__device__ __forceinline__ i32x4 ldsld(const int8_t* p) {
    return *reinterpret_cast<const i32x4*>(p);
}
#define FENCE asm volatile("" ::: "memory")
#define BAR   do { FENCE; __builtin_amdgcn_s_barrier(); FENCE; } while (0)

// W: vmcnt immediate at end of tile (-1 = no wait)
template<bool ST, int W>
__device__ __forceinline__ void tile_fn(
    const int8_t* __restrict__ aB, const int8_t* __restrict__ bB,  // frag bases (this tile's buf)
    i32x4 (&acc)[8][4],
    const int8_t* __restrict__ gA, const int8_t* __restrict__ gB,  // stage src (tile t+3)
    int8_t* lAn, int8_t* lBn,                                      // stage dest buf bases
    size_t r128, int t16)
{
    if (ST) {   // 4 G2L = 32 KB (A 2 slabs of 128 rows, B 2 slabs)
        G2L16(gA,        lAn + t16);
        G2L16(gA + r128, lAn + 8192 + t16);
        G2L16(gB,        lBn + t16);
        G2L16(gB + r128, lBn + 8192 + t16);
    }
    i32x4 b0 = ldsld(bB + 0*1024);
    i32x4 b1 = ldsld(bB + 1*1024);
    i32x4 b2 = ldsld(bB + 2*1024);
    i32x4 b3 = ldsld(bB + 3*1024);
    i32x4 a0 = ldsld(aB + 0*1024);
    i32x4 a1 = ldsld(aB + 1*1024);
    i32x4 a2 = ldsld(aB + 2*1024);
    i32x4 a3 = ldsld(aB + 3*1024);
    i32x4 a4 = ldsld(aB + 4*1024);
    i32x4 a5 = ldsld(aB + 5*1024);
    i32x4 a6 = ldsld(aB + 6*1024);
    i32x4 a7 = ldsld(aB + 7*1024);
    acc[0][0] = mfma16(a0, b0, acc[0][0]);
    acc[1][0] = mfma16(a1, b0, acc[1][0]);
    acc[2][0] = mfma16(a2, b0, acc[2][0]);
    acc[3][0] = mfma16(a3, b0, acc[3][0]);
    acc[4][0] = mfma16(a4, b0, acc[4][0]);
    acc[5][0] = mfma16(a5, b0, acc[5][0]);
    acc[6][0] = mfma16(a6, b0, acc[6][0]);
    acc[7][0] = mfma16(a7, b0, acc[7][0]);
    acc[0][1] = mfma16(a0, b1, acc[0][1]);
    acc[1][1] = mfma16(a1, b1, acc[1][1]);
    acc[2][1] = mfma16(a2, b1, acc[2][1]);
    acc[3][1] = mfma16(a3, b1, acc[3][1]);
    acc[4][1] = mfma16(a4, b1, acc[4][1]);
    acc[5][1] = mfma16(a5, b1, acc[5][1]);
    acc[6][1] = mfma16(a6, b1, acc[6][1]);
    acc[7][1] = mfma16(a7, b1, acc[7][1]);
    acc[0][2] = mfma16(a0, b2, acc[0][2]);
    acc[1][2] = mfma16(a1, b2, acc[1][2]);
    acc[2][2] = mfma16(a2, b2, acc[2][2]);
    acc[3][2] = mfma16(a3, b2, acc[3][2]);
    acc[4][2] = mfma16(a4, b2, acc[4][2]);
    acc[5][2] = mfma16(a5, b2, acc[5][2]);
    acc[6][2] = mfma16(a6, b2, acc[6][2]);
    acc[7][2] = mfma16(a7, b2, acc[7][2]);
    acc[0][3] = mfma16(a0, b3, acc[0][3]);
    acc[1][3] = mfma16(a1, b3, acc[1][3]);
    acc[2][3] = mfma16(a2, b3, acc[2][3]);
    acc[3][3] = mfma16(a3, b3, acc[3][3]);
    acc[4][3] = mfma16(a4, b3, acc[4][3]);
    acc[5][3] = mfma16(a5, b3, acc[5][3]);
    acc[6][3] = mfma16(a6, b3, acc[6][3]);
    acc[7][3] = mfma16(a7, b3, acc[7][3]);
    if (W == 8)      asm volatile("s_waitcnt vmcnt(8)" ::: "memory");
    else if (W == 4) asm volatile("s_waitcnt vmcnt(4)" ::: "memory");
    else if (W == 0) asm volatile("s_waitcnt vmcnt(0)" ::: "memory");
    if (W >= 0) BAR;
}

__global__ __launch_bounds__(512, 2)
void gemm_i8_k(const int8_t* __restrict__ A,    // [M][K]
               const int8_t* __restrict__ B,    // [N][K]
               const float*  __restrict__ sx,   // [M]
               const float*  __restrict__ sw,   // [N]
               const float*  __restrict__ bias, // [N]
               float* __restrict__ C,           // [M][N]
               int M, int N, int K)
{
    __shared__ int8_t lA[4][BM * BKB];   // 4 x 16 KiB
    __shared__ int8_t lB[4][BN * BKB];   // 4 x 16 KiB

    const int t    = threadIdx.x;
    const int lane = t & 63;
    const int wid  = t >> 6;
    const int wm   = wid >> 2;   // 0..1
    const int wn   = wid & 3;    // 0..3

    // bijective XCD swizzle (nwg = 1024, multiple of 8)
    const int nwg = (int)gridDim.x;
    const int bid = (int)blockIdx.x;
    const int swz = ((nwg & 7) == 0) ? ((bid & 7) * (nwg >> 3) + (bid >> 3)) : bid;
    const int nbn = N / BN;
    const int bm  = swz / nbn;
    const int bn  = swz % nbn;

    // fragment-read addressing: 64B rows, chunk kc = (c4 ^ ((fr>>1)&3))*16
    const int fr = lane & 15;
    const int c4 = lane >> 4;
    const int kc = ((c4 ^ ((fr >> 1) & 3)) << 4);
    const int aOff = (wm * 128 + fr) * BKB + kc;
    const int bOff = (wn * 64 + fr) * BKB + kc;
    const int8_t* aF[4] = { &lA[0][aOff], &lA[1][aOff], &lA[2][aOff], &lA[3][aOff] };
    const int8_t* bF[4] = { &lB[0][bOff], &lB[1][bOff], &lB[2][bOff], &lB[3][bOff] };
    int8_t* sA[4] = { &lA[0][0], &lA[1][0], &lA[2][0], &lA[3][0] };
    int8_t* sB[4] = { &lB[0][0], &lB[1][0], &lB[2][0], &lB[3][0] };

    // staging: thread t -> row t>>2 (0..127) of each 128-row slab, chunk t&3;
    // global source chunk pre-swizzled: cg = (t&3) ^ ((row>>1)&3) = (t&3)^((t>>3)&3)
    const int srow = t >> 2;
    const int scg  = (((t & 3) ^ ((t >> 3) & 3)) << 4);
    const int t16  = t * 16;
    const int8_t* pA = A + (size_t)(bm * BM + srow) * K + scg;
    const int8_t* pB = B + (size_t)(bn * BN + srow) * K + scg;
    const size_t r128 = (size_t)128 * K;

    // prologue: stage tiles 0,1,2 into bufs 0,1,2 (oldest-first issue order)
    #pragma unroll
    for (int tau = 0; tau < 3; ++tau) {
        const size_t ko = (size_t)tau * BKB;
        G2L16(pA + ko,        sA[tau] + t16);
        G2L16(pA + ko + r128, sA[tau] + 8192 + t16);
        G2L16(pB + ko,        sB[tau] + t16);
        G2L16(pB + ko + r128, sB[tau] + 8192 + t16);
    }
    asm volatile("s_waitcnt vmcnt(8)" ::: "memory");   // tile 0 resident; 1,2 in flight
    BAR;

    i32x4 acc[8][4] = {};

    const int NT = K / BKB;   // 64
    for (int tt = 0; tt < NT - 4; tt += 4) {
        tile_fn<true, 8>(aF[0], bF[0], acc, pA + (size_t)(tt + 3) * BKB, pB + (size_t)(tt + 3) * BKB, sA[3], sB[3], r128, t16);
        tile_fn<true, 8>(aF[1], bF[1], acc, pA + (size_t)(tt + 4) * BKB, pB + (size_t)(tt + 4) * BKB, sA[0], sB[0], r128, t16);
        tile_fn<true, 8>(aF[2], bF[2], acc, pA + (size_t)(tt + 5) * BKB, pB + (size_t)(tt + 5) * BKB, sA[1], sB[1], r128, t16);
        tile_fn<true, 8>(aF[3], bF[3], acc, pA + (size_t)(tt + 6) * BKB, pB + (size_t)(tt + 6) * BKB, sA[2], sB[2], r128, t16);
    }
    {   // tiles NT-4 .. NT-1 (60..63): stage only tile 63; ramp vmcnt 8->4->0->none
        tile_fn<true,  8>(aF[0], bF[0], acc, pA + (size_t)(NT - 1) * BKB, pB + (size_t)(NT - 1) * BKB, sA[3], sB[3], r128, t16);
        tile_fn<false, 4>(aF[1], bF[1], acc, pA, pB, sA[0], sB[0], r128, t16);
        tile_fn<false, 0>(aF[2], bF[2], acc, pA, pB, sA[1], sB[1], r128, t16);
        tile_fn<false,-1>(aF[3], bF[3], acc, pA, pB, sA[2], sB[2], r128, t16);
    }

    // epilogue: dequant + bias
    const int r0 = bm * BM + wm * 128 + (c4 << 2);
    const int c0 = bn * BN + wn * 64 + fr;
    #pragma unroll
    for (int ni = 0; ni < 4; ++ni) {
        const int c = c0 + ni * 16;
        const float swc = sw[c];
        const float bc  = bias[c];
        #pragma unroll
        for (int mi = 0; mi < 8; ++mi) {
            const int rb = r0 + mi * 16;
            #pragma unroll
            for (int j = 0; j < 4; ++j) {
                const int r = rb + j;
                C[(size_t)r * N + c] = (float)acc[mi][ni][j] * sx[r] * swc + bc;
            }
        }
    }
}

extern "C" void kernel_launch(void* const* d_in, const int* in_sizes, int n_in,
                              void* d_out, int out_size, void* d_ws, size_t ws_size,
                              hipStream_t stream) {
    const float* x    = (const float*)d_in[0];
    const float* w    = (const float*)d_in[1];
    const float* bias = (const float*)d_in[2];
    float* out = (float*)d_out;

    const int dout   = in_sizes[2];          // 16384
    const int din    = in_sizes[1] / dout;   // 4096
    const int tokens = in_sizes[0] / din;    // 4096

    char* ws = (char*)d_ws;
    float*  sx = (float*)ws;
    float*  sw = (float*)(ws + 16384);
    int8_t* xq = (int8_t*)(ws + 16384 + 65536);
    int8_t* wq = xq + (size_t)tokens * din;

    quant_rows_k<4096><<<tokens, 256, 0, stream>>>(x, xq, sx);
    quant_rows_k<4096><<<dout,   256, 0, stream>>>(w, wq, sw);

    const int grid = (tokens / BM) * (dout / BN);   // 16 * 64 = 1024
    gemm_i8_k<<<grid, 512, 0, stream>>>(xq, wq, sx, sw, bias, out, tokens, dout, din);
}